// Round 3
// baseline (475.223 us; speedup 1.0000x reference)
//
#include <hip/hip_runtime.h>

typedef unsigned short u16;
typedef unsigned int u32;
typedef __attribute__((ext_vector_type(8))) short short8;
typedef __attribute__((ext_vector_type(4))) float f32x4;

#define NB 64
#define NS 2048
#define ND 512
#define NU 256

__device__ __forceinline__ u16 f2b(float f) {
    u32 x = __float_as_uint(f);
    u32 r = (x + 0x7FFFu + ((x >> 16) & 1u)) >> 16;   // round-to-nearest-even
    return (u16)r;
}
__device__ __forceinline__ float fast_tanh(float x) {
    // tanh(x) = 1 - 2/(exp(2x)+1); exp overflow->inf gives correct +/-1 sat
    float e = __expf(2.0f * x);
    return 1.0f - 2.0f / (e + 1.0f);
}

// ---------------------------------------------------------------------------
// Kernel 1: cb[b][u] = sum_d q[b][d]*W2[d][u] + b1[u] + b2[u]   (all fp32)
// ---------------------------------------------------------------------------
__global__ __launch_bounds__(256) void cbias_kernel(
    const float* __restrict__ q, const float* __restrict__ W2,
    const float* __restrict__ b1, const float* __restrict__ b2,
    float* __restrict__ cb)
{
    int b = blockIdx.x, u = threadIdx.x;
    __shared__ float qs[ND];
    qs[u]       = q[b * ND + u];
    qs[u + 256] = q[b * ND + u + 256];
    __syncthreads();
    float acc = 0.f;
#pragma unroll 8
    for (int d = 0; d < ND; d++)
        acc += qs[d] * W2[d * NU + u];
    cb[b * NU + u] = acc + b1[u] + b2[u];
}

// ---------------------------------------------------------------------------
// Kernel 2: W1T[u][d] = bf16(W1[d][u])   (fp32 512x256 -> bf16 256x512)
// ---------------------------------------------------------------------------
__global__ __launch_bounds__(256) void transpose_kernel(
    const float* __restrict__ W1, u16* __restrict__ W1T)
{
    __shared__ float tile[64][65];
    int k0 = blockIdx.x * 64;   // 8 tiles along D
    int u0 = blockIdx.y * 64;   // 4 tiles along U
    for (int i = threadIdx.x; i < 4096; i += 256) {
        int r = i >> 6, c = i & 63;          // r: k, c: u
        tile[r][c] = W1[(k0 + r) * NU + u0 + c];
    }
    __syncthreads();
    for (int i = threadIdx.x; i < 4096; i += 256) {
        int r = i >> 6, c = i & 63;          // r: u, c: k
        W1T[(u0 + r) * ND + k0 + c] = f2b(tile[c][r]);
    }
}

// ---------------------------------------------------------------------------
// Kernel 3: scores[b*S+s] = sum_u tanh( (values[b,s,:]@W1)[u] + cb[b][u] )*V[u]
// MFMA GEMM: block tile M=128 x N=256(full U), K-loop over 512 in BK=32.
// 512 threads = 8 waves, wave grid 2x4, each wave 64x64 via 4x4 16x16x32 frags.
// A-side: fp32 values loaded as float4 pairs, RNE-packed to bf16 in LDS.
// ---------------------------------------------------------------------------
__global__ __launch_bounds__(512) void score_kernel(
    const float* __restrict__ values, // [64][2048][512] fp32
    const u16* __restrict__ W1T,      // [256][512] bf16
    const float* __restrict__ cb,     // [64][256]
    const float* __restrict__ V,      // [256]
    float* __restrict__ scores)       // [64*2048]
{
    const int tid  = threadIdx.x;
    const int lane = tid & 63;
    const int wave = tid >> 6;        // 0..7
    const int wm   = wave >> 2;       // 0..1  (M dim)
    const int wn   = wave & 3;        // 0..3  (N dim)
    const int m16  = lane & 15;
    const int quad = lane >> 4;

    const int mblk = blockIdx.x;              // 0..1023
    const int b    = mblk >> 4;               // 16 M-tiles per batch (2048/128)
    const size_t base_row = (size_t)mblk * 128;

    // padded stride 40 bf16 (80 B = 5x16B): b128 frag reads stay 16B-aligned
    // and spread across all 32 banks conflict-free
    __shared__ u16 At[128][40];
    __shared__ u16 Bt[256][40];
    __shared__ float cbs[NU];
    __shared__ float Vs[NU];
    __shared__ float rowsum[128];

    if (tid < 256) { cbs[tid] = cb[b * NU + tid]; Vs[tid] = V[tid]; }
    if (tid < 128) rowsum[tid] = 0.f;

    f32x4 acc[4][4] = {};

    const float* Abase = values + base_row * ND;
    const int arow = tid >> 2, aseg = tid & 3;   // A: 128 rows x 4 8-elem chunks

    for (int k0 = 0; k0 < ND; k0 += 32) {
        // stage A tile: 128 x 32 fp32 -> bf16 (RNE)
        {
            const float* src = Abase + (size_t)arow * ND + k0 + aseg * 8;
            float4 v0 = *(const float4*)src;
            float4 v1 = *(const float4*)(src + 4);
            union { u16 h[8]; uint4 q; } pk;
            pk.h[0] = f2b(v0.x); pk.h[1] = f2b(v0.y);
            pk.h[2] = f2b(v0.z); pk.h[3] = f2b(v0.w);
            pk.h[4] = f2b(v1.x); pk.h[5] = f2b(v1.y);
            pk.h[6] = f2b(v1.z); pk.h[7] = f2b(v1.w);
            *(uint4*)&At[arow][aseg * 8] = pk.q;
        }
        // stage B tile: 256 x 32 bf16 (from W1T, rows = u, contiguous k)
        {
            const int u = tid >> 2, seg = tid & 3;
            uint4 v0 = *(const uint4*)(W1T + (size_t)u * ND + k0 + seg * 8);
            uint4 v1 = *(const uint4*)(W1T + (size_t)(u + 128) * ND + k0 + seg * 8);
            *(uint4*)&Bt[u][seg * 8]       = v0;
            *(uint4*)&Bt[u + 128][seg * 8] = v1;
        }
        __syncthreads();

        short8 afr[4], bfr[4];
#pragma unroll
        for (int rb = 0; rb < 4; rb++)
            afr[rb] = *(const short8*)&At[wm * 64 + rb * 16 + m16][quad * 8];
#pragma unroll
        for (int cbk = 0; cbk < 4; cbk++)
            bfr[cbk] = *(const short8*)&Bt[wn * 64 + cbk * 16 + m16][quad * 8];
#pragma unroll
        for (int rb = 0; rb < 4; rb++)
#pragma unroll
            for (int cbk = 0; cbk < 4; cbk++)
                acc[rb][cbk] = __builtin_amdgcn_mfma_f32_16x16x32_bf16(
                    afr[rb], bfr[cbk], acc[rb][cbk], 0, 0, 0);
        __syncthreads();
    }

    // Epilogue: score contribution = tanh(pv + cb[c]) * V[c], reduce over c
    float cbv[4], vv[4];
#pragma unroll
    for (int cbk = 0; cbk < 4; cbk++) {
        int c = wn * 64 + cbk * 16 + m16;
        cbv[cbk] = cbs[c];
        vv[cbk]  = Vs[c];
    }
#pragma unroll
    for (int rb = 0; rb < 4; rb++) {
#pragma unroll
        for (int i = 0; i < 4; i++) {
            float s = 0.f;
#pragma unroll
            for (int cbk = 0; cbk < 4; cbk++)
                s += fast_tanh(acc[rb][cbk][i] + cbv[cbk]) * vv[cbk];
            // reduce across the 16 lanes that share a row (low 4 lane bits)
            s += __shfl_xor(s, 1, 64);
            s += __shfl_xor(s, 2, 64);
            s += __shfl_xor(s, 4, 64);
            s += __shfl_xor(s, 8, 64);
            if (m16 == 0)
                atomicAdd(&rowsum[wm * 64 + rb * 16 + quad * 4 + i], s);
        }
    }
    __syncthreads();
    if (tid < 128) scores[base_row + tid] = rowsum[tid];
}

// ---------------------------------------------------------------------------
// Kernel 4: softmax over S per batch (bV dropped: uniform shift)
// ---------------------------------------------------------------------------
__global__ __launch_bounds__(256) void softmax_kernel(
    const float* __restrict__ scores, float* __restrict__ attn)
{
    int b = blockIdx.x, tid = threadIdx.x;
    __shared__ float red[256];
    const float* s = scores + (size_t)b * NS;
    float v[8];
    float mx = -1e30f;
#pragma unroll
    for (int i = 0; i < 8; i++) { v[i] = s[tid + i * 256]; mx = fmaxf(mx, v[i]); }
    red[tid] = mx; __syncthreads();
    for (int off = 128; off > 0; off >>= 1) {
        if (tid < off) red[tid] = fmaxf(red[tid], red[tid + off]);
        __syncthreads();
    }
    mx = red[0]; __syncthreads();
    float sum = 0.f;
#pragma unroll
    for (int i = 0; i < 8; i++) { v[i] = __expf(v[i] - mx); sum += v[i]; }
    red[tid] = sum; __syncthreads();
    for (int off = 128; off > 0; off >>= 1) {
        if (tid < off) red[tid] += red[tid + off];
        __syncthreads();
    }
    float inv = 1.0f / red[0];
#pragma unroll
    for (int i = 0; i < 8; i++) attn[(size_t)b * NS + tid + i * 256] = v[i] * inv;
}

// ---------------------------------------------------------------------------
// Kernel 5: context partials: partial[b][sc][d] = sum_{s in chunk} attn*values
// grid (16 s-chunks, 64 batches), 256 thr: 4 s-rows in flight x 64 lanes x 8 d
// fp32 values end-to-end (output-critical path at full precision).
// ---------------------------------------------------------------------------
__global__ __launch_bounds__(256) void context_kernel(
    const float* __restrict__ values, const float* __restrict__ attn,
    float* __restrict__ partial)
{
    int sc = blockIdx.x, b = blockIdx.y, tid = threadIdx.x;
    int srow = tid >> 6;              // 0..3
    int d0 = (tid & 63) * 8;
    __shared__ float at[128];
    __shared__ float part[4][ND];
    if (tid < 128) at[tid] = attn[(size_t)b * NS + sc * 128 + tid];
    __syncthreads();
    float acc[8] = {0.f,0.f,0.f,0.f,0.f,0.f,0.f,0.f};
    const float* vb = values + ((size_t)b * NS + (size_t)sc * 128) * ND;
#pragma unroll 4
    for (int i = 0; i < 32; i++) {
        int sl = i * 4 + srow;
        float a = at[sl];
        float4 r0 = *(const float4*)(vb + (size_t)sl * ND + d0);
        float4 r1 = *(const float4*)(vb + (size_t)sl * ND + d0 + 4);
        acc[0] += a * r0.x; acc[1] += a * r0.y;
        acc[2] += a * r0.z; acc[3] += a * r0.w;
        acc[4] += a * r1.x; acc[5] += a * r1.y;
        acc[6] += a * r1.z; acc[7] += a * r1.w;
    }
#pragma unroll
    for (int j = 0; j < 8; j++) part[srow][d0 + j] = acc[j];
    __syncthreads();
    if (tid < 128) {
#pragma unroll
        for (int j = 0; j < 4; j++) {
            int d = tid * 4 + j;
            partial[((size_t)b * 16 + sc) * ND + d] =
                part[0][d] + part[1][d] + part[2][d] + part[3][d];
        }
    }
}

// ---------------------------------------------------------------------------
// Kernel 6: out[b][d] = sum_sc partial[b][sc][d]   (fp32 output — reference
// output dtype is float32; round-2 failure was writing packed bf16 here)
// ---------------------------------------------------------------------------
__global__ __launch_bounds__(256) void finalize_kernel(
    const float* __restrict__ partial, float* __restrict__ out)
{
    int idx = blockIdx.x * 256 + threadIdx.x;  // 0..32767
    int b = idx >> 9, d = idx & 511;
    float s = 0.f;
#pragma unroll
    for (int sc = 0; sc < 16; sc++)
        s += partial[((size_t)b * 16 + sc) * ND + d];
    out[idx] = s;
}

// ---------------------------------------------------------------------------
extern "C" void kernel_launch(void* const* d_in, const int* in_sizes, int n_in,
                              void* d_out, int out_size, void* d_ws, size_t ws_size,
                              hipStream_t stream)
{
    const float* q      = (const float*)d_in[0];   // [64][512]
    const float* values = (const float*)d_in[1];   // [64][2048][512]
    const float* W1     = (const float*)d_in[2];   // [512][256]
    const float* b1     = (const float*)d_in[3];   // [256]
    const float* W2     = (const float*)d_in[4];   // [512][256]
    const float* b2     = (const float*)d_in[5];   // [256]
    const float* V      = (const float*)d_in[6];   // [256]
    // d_in[7] = bV: uniform score shift -> softmax invariant, unused.

    char* ws = (char*)d_ws;
    float* cb      = (float*)(ws);                       //  65536 B
    u16*   W1T     = (u16*)  (ws + 65536);               // 262144 B
    float* scores  = (float*)(ws + 65536 + 262144);      // 524288 B
    float* attn    = (float*)(ws + 851968);              // 524288 B
    float* partial = (float*)(ws + 1376256);             // 2097152 B  (~3.5 MB total)

    hipLaunchKernelGGL(cbias_kernel, dim3(64), dim3(256), 0, stream, q, W2, b1, b2, cb);
    hipLaunchKernelGGL(transpose_kernel, dim3(8, 4), dim3(256), 0, stream, W1, W1T);
    hipLaunchKernelGGL(score_kernel, dim3(1024), dim3(512), 0, stream,
                       values, W1T, cb, V, scores);
    hipLaunchKernelGGL(softmax_kernel, dim3(64), dim3(256), 0, stream, scores, attn);
    hipLaunchKernelGGL(context_kernel, dim3(16, 64), dim3(256), 0, stream,
                       values, attn, partial);
    hipLaunchKernelGGL(finalize_kernel, dim3(128), dim3(256), 0, stream,
                       partial, (float*)d_out);
}